// Round 2
// baseline (1400.985 us; speedup 1.0000x reference)
//
#include <hip/hip_runtime.h>
#include <hip/hip_bf16.h>

// ---------- types ----------
typedef __attribute__((ext_vector_type(8))) short  bf16x8;
typedef __attribute__((ext_vector_type(4))) short  s16x4;
typedef __attribute__((ext_vector_type(4))) float  f32x4;

#define B_   8
#define T_   8192
#define D_   512
#define E_   4
#define K_   2048      // tokens per expert per batch
#define INNER_ 2048
#define M_TOK 16384    // tokens per expert across batches (8*2048)

// round-to-nearest-even f32 -> bf16 (bit pattern as short)
static __device__ __forceinline__ short f2bf(float f) {
    union { float f; unsigned int u; } a; a.f = f;
    unsigned int u = a.u;
    u += 0x7FFFu + ((u >> 16) & 1u);
    return (short)(u >> 16);
}

// ---------------------------------------------------------------------------
// weights f32 -> bf16 (w1: 2048x512, w2: 512x2048; both 1,048,576 elems)
// ---------------------------------------------------------------------------
__global__ __launch_bounds__(256) void convertw(const float* __restrict__ w1,
                                                const float* __restrict__ w2,
                                                short* __restrict__ o1,
                                                short* __restrict__ o2) {
    int i = (blockIdx.x * 256 + threadIdx.x) * 4;
    if (i < 1048576) {
        float4 a = *(const float4*)(w1 + i);
        s16x4 ra; ra.x = f2bf(a.x); ra.y = f2bf(a.y); ra.z = f2bf(a.z); ra.w = f2bf(a.w);
        *(s16x4*)(o1 + i) = ra;
        float4 b = *(const float4*)(w2 + i);
        s16x4 rb; rb.x = f2bf(b.x); rb.y = f2bf(b.y); rb.z = f2bf(b.z); rb.w = f2bf(b.w);
        *(s16x4*)(o2 + i) = rb;
    }
}

// ---------------------------------------------------------------------------
// routing: one block per batch. 4 sequential rounds of exact top-2048
// (desc by value, asc by index on ties) over not-yet-consumed tokens.
// Writes: perm[r'] (token idx), scale[r'] = alpha*p_e+1, probs output.
// r' = e*16384 + b*2048 + rank   (expert-major compute layout)
// output row g = b*8192 + e*2048 + rank
// ---------------------------------------------------------------------------
__global__ __launch_bounds__(1024) void route_kernel(const float* __restrict__ router_prob,
                                                     const float* __restrict__ alphaPtr,
                                                     int* __restrict__ perm,
                                                     float* __restrict__ scaleArr,
                                                     float* __restrict__ out_probs) {
    __shared__ unsigned long long keys[8192];   // 64 KB
    const int t = threadIdx.x;
    const int b = blockIdx.x;
    const size_t base = (size_t)b * T_;
    const float alphaV = *alphaPtr;
    unsigned int consMask = 0;   // bit j: token t*8+j consumed

    for (int e = 0; e < E_; ++e) {
        // build keys
        #pragma unroll
        for (int j = 0; j < 8; ++j) {
            int i = t * 8 + j;
            unsigned long long key = 0ull;
            if (!((consMask >> j) & 1u)) {
                float v = router_prob[(base + i) * E_ + e];
                unsigned int vb; __builtin_memcpy(&vb, &v, 4);
                key = (((unsigned long long)(vb + 1u)) << 13) | (unsigned long long)(8191 - i);
            }
            keys[i] = key;
        }
        // bitonic sort, descending
        for (int size = 2; size <= 8192; size <<= 1) {
            for (int stride = size >> 1; stride > 0; stride >>= 1) {
                __syncthreads();
                for (int i = t; i < 8192; i += 1024) {
                    int l = i ^ stride;
                    if (l > i) {
                        unsigned long long a = keys[i], c = keys[l];
                        bool desc = ((i & size) == 0);
                        if (desc ? (a < c) : (a > c)) { keys[i] = c; keys[l] = a; }
                    }
                }
            }
        }
        __syncthreads();
        // extract top 2048 (each thread: p = t and p = t+1024)
        int selIdx[2];
        #pragma unroll
        for (int q = 0; q < 2; ++q) {
            int p = t + q * 1024;
            unsigned long long key = keys[p];
            int idx = 8191 - (int)(key & 8191ull);
            selIdx[q] = idx;
            unsigned int vb = (unsigned int)(key >> 13) - 1u;
            float v; __builtin_memcpy(&v, &vb, 4);
            int rp_ = (e << 14) + (b << 11) + p;
            perm[rp_] = idx;
            scaleArr[rp_] = alphaV * v + 1.0f;
            size_t g = ((size_t)b << 13) + (e << 11) + p;
            float4 pr = *(const float4*)(router_prob + ((base + idx) << 2));
            *(float4*)(out_probs + (g << 2)) = pr;
        }
        __syncthreads();                  // all done reading keys
        // mark consumed via LDS reuse as flag bytes
        unsigned char* flags = (unsigned char*)keys;
        for (int i = t; i < 8192; i += 1024) flags[i] = 0;
        __syncthreads();
        flags[selIdx[0]] = 1;
        flags[selIdx[1]] = 1;
        __syncthreads();
        #pragma unroll
        for (int j = 0; j < 8; ++j)
            consMask |= ((unsigned int)flags[t * 8 + j]) << j;
        __syncthreads();
    }
}

// ---------------------------------------------------------------------------
// gather + LayerNorm. One wave per slot r'. Writes xn (bf16, [65536][512])
// and prefills out[g] = xi (residual; cols >= m stay xi).
// ---------------------------------------------------------------------------
__global__ __launch_bounds__(256) void gather_ln(const float* __restrict__ x,
                                                 const int* __restrict__ perm,
                                                 const float* __restrict__ ln_w,
                                                 const float* __restrict__ ln_b,
                                                 short* __restrict__ xn,
                                                 float* __restrict__ out_outs) {
    const int wv = threadIdx.x >> 6, lane = threadIdx.x & 63;
    const int rp_ = (blockIdx.x << 2) + wv;
    const int e = rp_ >> 14, rem = rp_ & 16383, b = rem >> 11, rank = rem & 2047;
    const int idx = perm[rp_];
    const float* xr = x + (((size_t)b << 13) + idx) * D_;
    const int d0 = lane << 3;
    float4 v0 = *(const float4*)(xr + d0);
    float4 v1 = *(const float4*)(xr + d0 + 4);

    float s = v0.x + v0.y + v0.z + v0.w + v1.x + v1.y + v1.z + v1.w;
    #pragma unroll
    for (int o = 32; o > 0; o >>= 1) s += __shfl_xor(s, o, 64);
    float mu = s * (1.0f / 512.0f);

    float a0 = v0.x - mu, a1 = v0.y - mu, a2 = v0.z - mu, a3 = v0.w - mu;
    float a4 = v1.x - mu, a5 = v1.y - mu, a6 = v1.z - mu, a7 = v1.w - mu;
    float q = a0*a0 + a1*a1 + a2*a2 + a3*a3 + a4*a4 + a5*a5 + a6*a6 + a7*a7;
    #pragma unroll
    for (int o = 32; o > 0; o >>= 1) q += __shfl_xor(q, o, 64);
    float rstd = rsqrtf(q * (1.0f / 512.0f) + 1e-5f);

    const size_t g = ((size_t)b << 13) + (e << 11) + rank;
    float* op = out_outs + g * D_ + d0;
    *(float4*)op       = v0;            // residual prefill
    *(float4*)(op + 4) = v1;

    float4 w0 = *(const float4*)(ln_w + d0);
    float4 w1 = *(const float4*)(ln_w + d0 + 4);
    float4 bb0 = *(const float4*)(ln_b + d0);
    float4 bb1 = *(const float4*)(ln_b + d0 + 4);
    bf16x8 hv;
    hv[0] = f2bf(a0 * rstd * w0.x + bb0.x);
    hv[1] = f2bf(a1 * rstd * w0.y + bb0.y);
    hv[2] = f2bf(a2 * rstd * w0.z + bb0.z);
    hv[3] = f2bf(a3 * rstd * w0.w + bb0.w);
    hv[4] = f2bf(a4 * rstd * w1.x + bb1.x);
    hv[5] = f2bf(a5 * rstd * w1.y + bb1.y);
    hv[6] = f2bf(a6 * rstd * w1.z + bb1.z);
    hv[7] = f2bf(a7 * rstd * w1.w + bb1.w);
    *(bf16x8*)(xn + (size_t)rp_ * D_ + d0) = hv;
}

// ---------------------------------------------------------------------------
// GEMM, C = A(MxK) * B(NxK)^T, both K-contiguous bf16. M = 16384 fixed.
// 128x128 tile, BK=64, 4 waves, 4x4 frags of mfma_f32_16x16x32_bf16 per wave.
// MODE 1: h = bf16(gelu(C + l1_b[col]))              (N=2048, K=m)
// MODE 2: out[g, col] += scale[r'] * (C + l2_b[col]) (N=m,    K=2048)
// ---------------------------------------------------------------------------
template <int MODE>
__global__ __launch_bounds__(256) void gemm_bt(const short* __restrict__ A,
                                               const short* __restrict__ B,
                                               int N, int K, int lda, int ldb,
                                               const float* __restrict__ bias,
                                               short* __restrict__ H,
                                               float* __restrict__ Out,
                                               const float* __restrict__ scaleArr,
                                               int expert) {
    __shared__ short As[128 * 64];
    __shared__ short Bs[128 * 64];
    const int t = threadIdx.x;
    const int tile_n = blockIdx.x << 7;
    const int tile_m = blockIdx.y << 7;
    const int lane = t & 63, wave = t >> 6;
    const int wm = (wave >> 1) << 6, wn = (wave & 1) << 6;
    const int lrow = lane & 15, lk = (lane >> 4) << 3;

    f32x4 acc[4][4];
    #pragma unroll
    for (int i = 0; i < 4; ++i)
        #pragma unroll
        for (int j = 0; j < 4; ++j)
            acc[i][j] = (f32x4){0.f, 0.f, 0.f, 0.f};

    for (int k0 = 0; k0 < K; k0 += 64) {
        #pragma unroll
        for (int j = 0; j < 4; ++j) {
            int u = (j << 8) + t;            // 0..1023 units of 8 bf16
            int r = u >> 3, kb = (u & 7) << 3;
            *(bf16x8*)(As + (u << 3)) =
                *(const bf16x8*)(A + (size_t)(tile_m + r) * lda + k0 + kb);
            bf16x8 bv = (bf16x8){0, 0, 0, 0, 0, 0, 0, 0};
            int brow = tile_n + r;
            if (brow < N)
                bv = *(const bf16x8*)(B + (size_t)brow * ldb + k0 + kb);
            *(bf16x8*)(Bs + (u << 3)) = bv;
        }
        __syncthreads();
        bf16x8 af[4][2], bfr[4][2];
        #pragma unroll
        for (int f = 0; f < 4; ++f)
            #pragma unroll
            for (int kk = 0; kk < 2; ++kk) {
                af[f][kk]  = *(const bf16x8*)(As + ((wm + (f << 4) + lrow) << 6) + (kk << 5) + lk);
                bfr[f][kk] = *(const bf16x8*)(Bs + ((wn + (f << 4) + lrow) << 6) + (kk << 5) + lk);
            }
        #pragma unroll
        for (int kk = 0; kk < 2; ++kk)
            #pragma unroll
            for (int fm = 0; fm < 4; ++fm)
                #pragma unroll
                for (int fn = 0; fn < 4; ++fn)
                    acc[fm][fn] = __builtin_amdgcn_mfma_f32_16x16x32_bf16(
                        af[fm][kk], bfr[fn][kk], acc[fm][fn], 0, 0, 0);
        __syncthreads();
    }

    #pragma unroll
    for (int fm = 0; fm < 4; ++fm) {
        #pragma unroll
        for (int fn = 0; fn < 4; ++fn) {
            #pragma unroll
            for (int j = 0; j < 4; ++j) {
                int row = tile_m + wm + (fm << 4) + ((lane >> 4) << 2) + j;  // token (expert-local)
                int col = tile_n + wn + (fn << 4) + (lane & 15);
                float v = acc[fm][fn][j];
                if (MODE == 1) {
                    v += bias[col];
                    v = 0.5f * v * (1.0f + erff(v * 0.7071067811865475f));
                    H[(size_t)row * (size_t)INNER_ + col] = f2bf(v);
                } else {
                    if (col < N) {
                        int bb = row >> 11, rank = row & 2047;
                        float sc = scaleArr[(expert << 14) + row];
                        float* p = Out + (((size_t)bb << 13) + (expert << 11) + rank) * D_ + col;
                        *p += sc * (v + bias[col]);
                    }
                }
            }
        }
    }
}

// ---------------------------------------------------------------------------
extern "C" void kernel_launch(void* const* d_in, const int* in_sizes, int n_in,
                              void* d_out, int out_size, void* d_ws, size_t ws_size,
                              hipStream_t stream) {
    const float* x           = (const float*)d_in[0];
    const float* router_prob = (const float*)d_in[1];
    const float* alpha       = (const float*)d_in[2];
    const float* ln_w        = (const float*)d_in[3];
    const float* ln_b        = (const float*)d_in[4];
    const float* l1_w        = (const float*)d_in[5];
    const float* l1_b        = (const float*)d_in[6];
    const float* l2_w        = (const float*)d_in[7];
    const float* l2_b        = (const float*)d_in[8];

    float* out       = (float*)d_out;
    float* out_probs = out + (size_t)B_ * T_ * D_;    // 33,554,432 floats in

    char* ws = (char*)d_ws;
    int*   perm  = (int*)(ws);                                    // 256 KB
    float* scale = (float*)(ws + (1u << 18));                     // 256 KB
    short* w1b   = (short*)(ws + (2u << 18));                     // 2 MB
    short* w2b   = (short*)(ws + (2u << 18) + (1u << 21));        // 2 MB
    short* xn    = (short*)(ws + (2u << 18) + (2u << 21));        // 64 MB
    short* h     = (short*)(ws + (2u << 18) + (2u << 21) + (1u << 26)); // 64 MB

    convertw<<<1024, 256, 0, stream>>>(l1_w, l2_w, w1b, w2b);
    route_kernel<<<8, 1024, 0, stream>>>(router_prob, alpha, perm, scale, out_probs);
    gather_ln<<<16384, 256, 0, stream>>>(x, perm, ln_w, ln_b, xn, out);

    for (int e = 0; e < E_; ++e) {
        int m = D_ >> e;   // 512, 256, 128, 64
        gemm_bt<1><<<dim3(INNER_ / 128, M_TOK / 128), 256, 0, stream>>>(
            xn + ((size_t)e * M_TOK) * D_, w1b, INNER_, m, D_, D_, l1_b, h,
            nullptr, nullptr, 0);
        gemm_bt<2><<<dim3((m + 127) >> 7, M_TOK / 128), 256, 0, stream>>>(
            h, w2b, m, INNER_, INNER_, INNER_, l2_b, nullptr, out, scale, e);
    }
}

// Round 4
// 820.479 us; speedup vs baseline: 1.7075x; 1.7075x over previous
//
#include <hip/hip_runtime.h>
#include <hip/hip_bf16.h>

// ---------- types ----------
typedef __attribute__((ext_vector_type(8))) short  bf16x8;
typedef __attribute__((ext_vector_type(4))) short  s16x4;
typedef __attribute__((ext_vector_type(4))) float  f32x4;
typedef unsigned long long u64;

#define B_   8
#define T_   8192
#define D_   512
#define E_   4
#define INNER_ 2048
#define M_TOK 16384    // tokens per expert across batches (8*2048)

// round-to-nearest-even f32 -> bf16 (bit pattern as short)
static __device__ __forceinline__ short f2bf(float f) {
    union { float f; unsigned int u; } a; a.f = f;
    unsigned int u = a.u;
    u += 0x7FFFu + ((u >> 16) & 1u);
    return (short)(u >> 16);
}

static __device__ __forceinline__ void cswap(u64& a, u64& b, bool desc) {
    if (desc ? (a < b) : (a > b)) { u64 t = a; a = b; b = t; }
}

// ---------------------------------------------------------------------------
// weights f32 -> bf16
// ---------------------------------------------------------------------------
__global__ __launch_bounds__(256) void convertw(const float* __restrict__ w1,
                                                const float* __restrict__ w2,
                                                short* __restrict__ o1,
                                                short* __restrict__ o2) {
    int i = (blockIdx.x * 256 + threadIdx.x) * 4;
    if (i < 1048576) {
        float4 a = *(const float4*)(w1 + i);
        s16x4 ra; ra.x = f2bf(a.x); ra.y = f2bf(a.y); ra.z = f2bf(a.z); ra.w = f2bf(a.w);
        *(s16x4*)(o1 + i) = ra;
        float4 b = *(const float4*)(w2 + i);
        s16x4 rb; rb.x = f2bf(b.x); rb.y = f2bf(b.y); rb.z = f2bf(b.z); rb.w = f2bf(b.w);
        *(s16x4*)(o2 + i) = rb;
    }
}

// ---------------------------------------------------------------------------
// sort_kernel: one block per (batch, expert) -- 32 independent full sorts of
// 8192 packed keys ((vbits+1)<<13)|(8191-idx), descending (value desc, idx asc).
// Bitonic; strides <=4 fused in registers (thread owns 8 contiguous elems).
// ---------------------------------------------------------------------------
__global__ __launch_bounds__(1024) void sort_kernel(const float* __restrict__ rp,
                                                    u64* __restrict__ sorted) {
    __shared__ u64 keys[8192];
    const int t = threadIdx.x;
    const int b = blockIdx.x >> 2, e = blockIdx.x & 3;
    const size_t base = (size_t)b * T_;

    u64 k[8];
    #pragma unroll
    for (int j = 0; j < 8; ++j) {
        int i = (t << 3) + j;
        float v = rp[(base + i) * E_ + e];
        unsigned vb; __builtin_memcpy(&vb, &v, 4);
        k[j] = (((u64)(vb + 1u)) << 13) | (u64)(8191 - i);
    }
    // in-register bitonic: sizes 2, 4, 8 (directions by global element index)
    cswap(k[0], k[1], true);  cswap(k[2], k[3], false);
    cswap(k[4], k[5], true);  cswap(k[6], k[7], false);
    cswap(k[0], k[2], true);  cswap(k[1], k[3], true);
    cswap(k[4], k[6], false); cswap(k[5], k[7], false);
    cswap(k[0], k[1], true);  cswap(k[2], k[3], true);
    cswap(k[4], k[5], false); cswap(k[6], k[7], false);
    {
        bool d8 = ((t & 1) == 0);
        cswap(k[0], k[4], d8); cswap(k[1], k[5], d8); cswap(k[2], k[6], d8); cswap(k[3], k[7], d8);
        cswap(k[0], k[2], d8); cswap(k[1], k[3], d8); cswap(k[4], k[6], d8); cswap(k[5], k[7], d8);
        cswap(k[0], k[1], d8); cswap(k[2], k[3], d8); cswap(k[4], k[5], d8); cswap(k[6], k[7], d8);
    }
    #pragma unroll
    for (int j = 0; j < 8; ++j) keys[(t << 3) + j] = k[j];

    for (int size = 16; size <= 8192; size <<= 1) {
        for (int stride = size >> 1; stride >= 8; stride >>= 1) {
            __syncthreads();
            #pragma unroll
            for (int q = 0; q < 4; ++q) {
                int p = (q << 10) + t;                         // pair id 0..4095
                int i = ((p & ~(stride - 1)) << 1) | (p & (stride - 1));
                int l = i | stride;
                bool desc = ((i & size) == 0);
                u64 a = keys[i], c = keys[l];
                if (desc ? (a < c) : (a > c)) { keys[i] = c; keys[l] = a; }
            }
        }
        // fused local phase: strides 4,2,1 (uniform direction per 8-block)
        __syncthreads();
        #pragma unroll
        for (int j = 0; j < 8; ++j) k[j] = keys[(t << 3) + j];
        bool d = (((t << 3) & size) == 0);
        cswap(k[0], k[4], d); cswap(k[1], k[5], d); cswap(k[2], k[6], d); cswap(k[3], k[7], d);
        cswap(k[0], k[2], d); cswap(k[1], k[3], d); cswap(k[4], k[6], d); cswap(k[5], k[7], d);
        cswap(k[0], k[1], d); cswap(k[2], k[3], d); cswap(k[4], k[5], d); cswap(k[6], k[7], d);
        #pragma unroll
        for (int j = 0; j < 8; ++j) keys[(t << 3) + j] = k[j];
    }
    __syncthreads();
    u64* dst = sorted + ((size_t)blockIdx.x << 13);
    #pragma unroll
    for (int j = 0; j < 8; ++j) {
        int i = (j << 10) + t;
        dst[i] = keys[i];
    }
}

// ---------------------------------------------------------------------------
// select_kernel: one block per batch. Sequential over experts: walk sorted
// list, prefix-scan not-consumed flags, take rank<2048, mark consumed.
// ---------------------------------------------------------------------------
__global__ __launch_bounds__(1024) void select_kernel(const float* __restrict__ rp,
                                                      const u64* __restrict__ sorted,
                                                      const float* __restrict__ alphaPtr,
                                                      int* __restrict__ perm,
                                                      float* __restrict__ scaleArr,
                                                      float* __restrict__ out_probs) {
    __shared__ unsigned char cons[8192];
    __shared__ int wsum[16];
    __shared__ int woff[16];
    const int t = threadIdx.x, b = blockIdx.x;
    const int lane = t & 63, wv = t >> 6;
    const size_t base = (size_t)b * T_;
    const float alphaV = *alphaPtr;

    #pragma unroll
    for (int j = 0; j < 8; ++j) cons[(t << 3) + j] = 0;
    __syncthreads();

    for (int e = 0; e < E_; ++e) {
        const u64* sk = sorted + (((size_t)(b << 2) + e) << 13);
        u64 k[8]; int idx[8]; int f[8];
        int s = 0;
        #pragma unroll
        for (int j = 0; j < 8; ++j) {
            k[j] = sk[(t << 3) + j];
            idx[j] = 8191 - (int)(k[j] & 8191ull);
            f[j] = cons[idx[j]] ? 0 : 1;
            s += f[j];
        }
        // wave inclusive scan of per-thread sums
        int inc = s;
        #pragma unroll
        for (int o = 1; o < 64; o <<= 1) {
            int v = __shfl_up(inc, o, 64);
            if (lane >= o) inc += v;
        }
        if (lane == 63) wsum[wv] = inc;
        __syncthreads();
        if (t == 0) {
            int acc = 0;
            for (int w = 0; w < 16; ++w) { int v = wsum[w]; woff[w] = acc; acc += v; }
        }
        __syncthreads();
        int off = woff[wv] + (inc - s);   // thread-exclusive prefix
        #pragma unroll
        for (int j = 0; j < 8; ++j) {
            if (f[j] && off < 2048) {
                int rank = off;
                unsigned vb = (unsigned)(k[j] >> 13) - 1u;
                float v; __builtin_memcpy(&v, &vb, 4);
                int rpos = (e << 14) + (b << 11) + rank;
                perm[rpos] = idx[j];
                scaleArr[rpos] = alphaV * v + 1.0f;
                size_t g = ((size_t)b << 13) + (e << 11) + rank;
                float4 pr = *(const float4*)(rp + ((base + idx[j]) << 2));
                *(float4*)(out_probs + (g << 2)) = pr;
                cons[idx[j]] = 1;
            }
            off += f[j];
        }
        __syncthreads();
    }
}

// ---------------------------------------------------------------------------
// gather + LayerNorm. One wave per slot r'. Writes xn (bf16, [65536][512])
// and prefills out[g] = xi (residual; cols >= m stay xi).
// ---------------------------------------------------------------------------
__global__ __launch_bounds__(256) void gather_ln(const float* __restrict__ x,
                                                 const int* __restrict__ perm,
                                                 const float* __restrict__ ln_w,
                                                 const float* __restrict__ ln_b,
                                                 short* __restrict__ xn,
                                                 float* __restrict__ out_outs) {
    const int wv = threadIdx.x >> 6, lane = threadIdx.x & 63;
    const int rp_ = (blockIdx.x << 2) + wv;
    const int e = rp_ >> 14, rem = rp_ & 16383, b = rem >> 11, rank = rem & 2047;
    const int idx = perm[rp_];
    const float* xr = x + (((size_t)b << 13) + idx) * D_;
    const int d0 = lane << 3;
    float4 v0 = *(const float4*)(xr + d0);
    float4 v1 = *(const float4*)(xr + d0 + 4);

    float s = v0.x + v0.y + v0.z + v0.w + v1.x + v1.y + v1.z + v1.w;
    #pragma unroll
    for (int o = 32; o > 0; o >>= 1) s += __shfl_xor(s, o, 64);
    float mu = s * (1.0f / 512.0f);

    float a0 = v0.x - mu, a1 = v0.y - mu, a2 = v0.z - mu, a3 = v0.w - mu;
    float a4 = v1.x - mu, a5 = v1.y - mu, a6 = v1.z - mu, a7 = v1.w - mu;
    float q = a0*a0 + a1*a1 + a2*a2 + a3*a3 + a4*a4 + a5*a5 + a6*a6 + a7*a7;
    #pragma unroll
    for (int o = 32; o > 0; o >>= 1) q += __shfl_xor(q, o, 64);
    float rstd = rsqrtf(q * (1.0f / 512.0f) + 1e-5f);

    const size_t g = ((size_t)b << 13) + (e << 11) + rank;
    float* op = out_outs + g * D_ + d0;
    *(float4*)op       = v0;            // residual prefill
    *(float4*)(op + 4) = v1;

    float4 w0 = *(const float4*)(ln_w + d0);
    float4 w1 = *(const float4*)(ln_w + d0 + 4);
    float4 bb0 = *(const float4*)(ln_b + d0);
    float4 bb1 = *(const float4*)(ln_b + d0 + 4);
    bf16x8 hv;
    hv[0] = f2bf(a0 * rstd * w0.x + bb0.x);
    hv[1] = f2bf(a1 * rstd * w0.y + bb0.y);
    hv[2] = f2bf(a2 * rstd * w0.z + bb0.z);
    hv[3] = f2bf(a3 * rstd * w0.w + bb0.w);
    hv[4] = f2bf(a4 * rstd * w1.x + bb1.x);
    hv[5] = f2bf(a5 * rstd * w1.y + bb1.y);
    hv[6] = f2bf(a6 * rstd * w1.z + bb1.z);
    hv[7] = f2bf(a7 * rstd * w1.w + bb1.w);
    *(bf16x8*)(xn + (size_t)rp_ * D_ + d0) = hv;
}

// ---------------------------------------------------------------------------
// GEMM, C = A(MxK) * B(NxK)^T, K-contiguous bf16. global_load_lds staging.
// 128x128 tile, BK=64, 4 waves, 4x4 frags of mfma_f32_16x16x32_bf16.
// MODE 1: h = bf16(gelu(C + l1_b[col]))              (N=2048, K=m)
// MODE 2: out[g, col] += scale[r'] * (C + l2_b[col]) (N=m,    K=2048)
// NOTE: B rows beyond N (only e=3, m=64) load garbage from in-bounds w2b
// rows; those columns are masked at store (col<N), so harmless.
// ---------------------------------------------------------------------------
template <int MODE>
__global__ __launch_bounds__(256) void gemm_bt(const short* __restrict__ A,
                                               const short* __restrict__ B,
                                               int N, int K, int lda, int ldb,
                                               const float* __restrict__ bias,
                                               short* __restrict__ H,
                                               float* __restrict__ Out,
                                               const float* __restrict__ scaleArr,
                                               int expert) {
    __shared__ short As[128 * 64];
    __shared__ short Bs[128 * 64];
    const int t = threadIdx.x;
    const int tile_n = blockIdx.x << 7;
    const int tile_m = blockIdx.y << 7;
    const int lane = t & 63, wave = t >> 6;
    const int wm = (wave >> 1) << 6, wn = (wave & 1) << 6;
    const int lrow = lane & 15, lk = (lane >> 4) << 3;
    const int ldsRow = lane >> 3;          // 0..7  (row within 8-row chunk)
    const int ldsCol = (lane & 7) << 3;    // 0..56 (element offset)

    f32x4 acc[4][4];
    #pragma unroll
    for (int i = 0; i < 4; ++i)
        #pragma unroll
        for (int j = 0; j < 4; ++j)
            acc[i][j] = (f32x4){0.f, 0.f, 0.f, 0.f};

    for (int k0 = 0; k0 < K; k0 += 64) {
        #pragma unroll
        for (int q = 0; q < 4; ++q) {
            int c = (wave << 2) + q;       // chunk 0..15 (8 rows each)
            const short* ga = A + (size_t)(tile_m + (c << 3) + ldsRow) * lda + k0 + ldsCol;
            __builtin_amdgcn_global_load_lds(
                (const __attribute__((address_space(1))) unsigned int*)ga,
                (__attribute__((address_space(3))) unsigned int*)(As + (c << 9)),
                16, 0, 0);
            const short* gb = B + (size_t)(tile_n + (c << 3) + ldsRow) * ldb + k0 + ldsCol;
            __builtin_amdgcn_global_load_lds(
                (const __attribute__((address_space(1))) unsigned int*)gb,
                (__attribute__((address_space(3))) unsigned int*)(Bs + (c << 9)),
                16, 0, 0);
        }
        __syncthreads();
        bf16x8 af[4][2], bfr[4][2];
        #pragma unroll
        for (int f = 0; f < 4; ++f)
            #pragma unroll
            for (int kk = 0; kk < 2; ++kk) {
                af[f][kk]  = *(const bf16x8*)(As + ((wm + (f << 4) + lrow) << 6) + (kk << 5) + lk);
                bfr[f][kk] = *(const bf16x8*)(Bs + ((wn + (f << 4) + lrow) << 6) + (kk << 5) + lk);
            }
        #pragma unroll
        for (int kk = 0; kk < 2; ++kk)
            #pragma unroll
            for (int fm = 0; fm < 4; ++fm)
                #pragma unroll
                for (int fn = 0; fn < 4; ++fn)
                    acc[fm][fn] = __builtin_amdgcn_mfma_f32_16x16x32_bf16(
                        af[fm][kk], bfr[fn][kk], acc[fm][fn], 0, 0, 0);
        __syncthreads();
    }

    #pragma unroll
    for (int fm = 0; fm < 4; ++fm) {
        #pragma unroll
        for (int fn = 0; fn < 4; ++fn) {
            #pragma unroll
            for (int j = 0; j < 4; ++j) {
                int row = tile_m + wm + (fm << 4) + ((lane >> 4) << 2) + j;  // token (expert-local)
                int col = tile_n + wn + (fn << 4) + (lane & 15);
                float v = acc[fm][fn][j];
                if (MODE == 1) {
                    v += bias[col];
                    v = 0.5f * v * (1.0f + erff(v * 0.7071067811865475f));
                    H[(size_t)row * (size_t)INNER_ + col] = f2bf(v);
                } else {
                    if (col < N) {
                        int bb = row >> 11, rank = row & 2047;
                        float sc = scaleArr[(expert << 14) + row];
                        float* p = Out + (((size_t)bb << 13) + (expert << 11) + rank) * D_ + col;
                        *p += sc * (v + bias[col]);
                    }
                }
            }
        }
    }
}

// ---------------------------------------------------------------------------
extern "C" void kernel_launch(void* const* d_in, const int* in_sizes, int n_in,
                              void* d_out, int out_size, void* d_ws, size_t ws_size,
                              hipStream_t stream) {
    const float* x           = (const float*)d_in[0];
    const float* router_prob = (const float*)d_in[1];
    const float* alpha       = (const float*)d_in[2];
    const float* ln_w        = (const float*)d_in[3];
    const float* ln_b        = (const float*)d_in[4];
    const float* l1_w        = (const float*)d_in[5];
    const float* l1_b        = (const float*)d_in[6];
    const float* l2_w        = (const float*)d_in[7];
    const float* l2_b        = (const float*)d_in[8];

    float* out       = (float*)d_out;
    float* out_probs = out + (size_t)B_ * T_ * D_;    // 33,554,432 floats in

    char* ws = (char*)d_ws;
    int*   perm  = (int*)(ws);                                    // 256 KB
    float* scale = (float*)(ws + (1u << 18));                     // 256 KB
    short* w1b   = (short*)(ws + (2u << 18));                     // 2 MB
    short* w2b   = (short*)(ws + (2u << 18) + (1u << 21));        // 2 MB
    short* xn    = (short*)(ws + (2u << 18) + (2u << 21));        // 64 MB
    short* h     = (short*)(ws + (2u << 18) + (2u << 21) + (1u << 26)); // 64 MB
    u64*   sorted = (u64*)h;   // alias: sorted keys used only before h is written

    convertw<<<1024, 256, 0, stream>>>(l1_w, l2_w, w1b, w2b);
    sort_kernel<<<32, 1024, 0, stream>>>(router_prob, sorted);
    select_kernel<<<8, 1024, 0, stream>>>(router_prob, sorted, alpha, perm, scale, out_probs);
    gather_ln<<<16384, 256, 0, stream>>>(x, perm, ln_w, ln_b, xn, out);

    for (int e = 0; e < E_; ++e) {
        int m = D_ >> e;   // 512, 256, 128, 64
        gemm_bt<1><<<dim3(INNER_ / 128, M_TOK / 128), 256, 0, stream>>>(
            xn + ((size_t)e * M_TOK) * D_, w1b, INNER_, m, D_, D_, l1_b, h,
            nullptr, nullptr, 0);
        gemm_bt<2><<<dim3((m + 127) >> 7, M_TOK / 128), 256, 0, stream>>>(
            h, w2b, m, INNER_, INNER_, INNER_, l2_b, nullptr, out, scale, e);
    }
}

// Round 8
// 812.710 us; speedup vs baseline: 1.7238x; 1.0096x over previous
//
#include <hip/hip_runtime.h>
#include <hip/hip_bf16.h>

// ---------- types ----------
typedef __attribute__((ext_vector_type(8))) short  bf16x8;
typedef __attribute__((ext_vector_type(4))) short  s16x4;
typedef __attribute__((ext_vector_type(4))) float  f32x4;
typedef unsigned long long u64;

#define B_   8
#define T_   8192
#define D_   512
#define E_   4
#define INNER_ 2048
#define M_TOK 16384    // tokens per expert across batches (8*2048)

// round-to-nearest-even f32 -> bf16 (bit pattern as short)
static __device__ __forceinline__ short f2bf(float f) {
    union { float f; unsigned int u; } a; a.f = f;
    unsigned int u = a.u;
    u += 0x7FFFu + ((u >> 16) & 1u);
    return (short)(u >> 16);
}

static __device__ __forceinline__ void cswap(u64& a, u64& b, bool desc) {
    if (desc ? (a < b) : (a > b)) { u64 t = a; a = b; b = t; }
}

// ---------------------------------------------------------------------------
// weights f32 -> bf16
// ---------------------------------------------------------------------------
__global__ __launch_bounds__(256) void convertw(const float* __restrict__ w1,
                                                const float* __restrict__ w2,
                                                short* __restrict__ o1,
                                                short* __restrict__ o2) {
    int i = (blockIdx.x * 256 + threadIdx.x) * 4;
    if (i < 1048576) {
        float4 a = *(const float4*)(w1 + i);
        s16x4 ra; ra.x = f2bf(a.x); ra.y = f2bf(a.y); ra.z = f2bf(a.z); ra.w = f2bf(a.w);
        *(s16x4*)(o1 + i) = ra;
        float4 b = *(const float4*)(w2 + i);
        s16x4 rb; rb.x = f2bf(b.x); rb.y = f2bf(b.y); rb.z = f2bf(b.z); rb.w = f2bf(b.w);
        *(s16x4*)(o2 + i) = rb;
    }
}

// ---------------------------------------------------------------------------
// sort_kernel: one block per (batch, expert) -- 32 independent full sorts of
// 8192 packed keys ((vbits+1)<<13)|(8191-idx), descending (value desc, idx asc).
// ---------------------------------------------------------------------------
__global__ __launch_bounds__(1024) void sort_kernel(const float* __restrict__ rp,
                                                    u64* __restrict__ sorted) {
    __shared__ u64 keys[8192];
    const int t = threadIdx.x;
    const int b = blockIdx.x >> 2, e = blockIdx.x & 3;
    const size_t base = (size_t)b * T_;

    u64 k[8];
    #pragma unroll
    for (int j = 0; j < 8; ++j) {
        int i = (t << 3) + j;
        float v = rp[(base + i) * E_ + e];
        unsigned vb; __builtin_memcpy(&vb, &v, 4);
        k[j] = (((u64)(vb + 1u)) << 13) | (u64)(8191 - i);
    }
    // in-register bitonic: sizes 2, 4, 8
    cswap(k[0], k[1], true);  cswap(k[2], k[3], false);
    cswap(k[4], k[5], true);  cswap(k[6], k[7], false);
    cswap(k[0], k[2], true);  cswap(k[1], k[3], true);
    cswap(k[4], k[6], false); cswap(k[5], k[7], false);
    cswap(k[0], k[1], true);  cswap(k[2], k[3], true);
    cswap(k[4], k[5], false); cswap(k[6], k[7], false);
    {
        bool d8 = ((t & 1) == 0);
        cswap(k[0], k[4], d8); cswap(k[1], k[5], d8); cswap(k[2], k[6], d8); cswap(k[3], k[7], d8);
        cswap(k[0], k[2], d8); cswap(k[1], k[3], d8); cswap(k[4], k[6], d8); cswap(k[5], k[7], d8);
        cswap(k[0], k[1], d8); cswap(k[2], k[3], d8); cswap(k[4], k[5], d8); cswap(k[6], k[7], d8);
    }
    #pragma unroll
    for (int j = 0; j < 8; ++j) keys[(t << 3) + j] = k[j];

    for (int size = 16; size <= 8192; size <<= 1) {
        for (int stride = size >> 1; stride >= 8; stride >>= 1) {
            __syncthreads();
            #pragma unroll
            for (int q = 0; q < 4; ++q) {
                int p = (q << 10) + t;                         // pair id 0..4095
                int i = ((p & ~(stride - 1)) << 1) | (p & (stride - 1));
                int l = i | stride;
                bool desc = ((i & size) == 0);
                u64 a = keys[i], c = keys[l];
                if (desc ? (a < c) : (a > c)) { keys[i] = c; keys[l] = a; }
            }
        }
        // fused local phase: strides 4,2,1 (uniform direction per 8-block)
        __syncthreads();
        #pragma unroll
        for (int j = 0; j < 8; ++j) k[j] = keys[(t << 3) + j];
        bool d = (((t << 3) & size) == 0);
        cswap(k[0], k[4], d); cswap(k[1], k[5], d); cswap(k[2], k[6], d); cswap(k[3], k[7], d);
        cswap(k[0], k[2], d); cswap(k[1], k[3], d); cswap(k[4], k[6], d); cswap(k[5], k[7], d);
        cswap(k[0], k[1], d); cswap(k[2], k[3], d); cswap(k[4], k[5], d); cswap(k[6], k[7], d);
        #pragma unroll
        for (int j = 0; j < 8; ++j) keys[(t << 3) + j] = k[j];
    }
    __syncthreads();
    u64* dst = sorted + ((size_t)blockIdx.x << 13);
    #pragma unroll
    for (int j = 0; j < 8; ++j) {
        int i = (j << 10) + t;
        dst[i] = keys[i];
    }
}

// ---------------------------------------------------------------------------
// select_kernel: one block per batch. Sequential over experts: walk sorted
// list, prefix-scan not-consumed flags, take rank<2048, mark consumed.
// ---------------------------------------------------------------------------
__global__ __launch_bounds__(1024) void select_kernel(const float* __restrict__ rp,
                                                      const u64* __restrict__ sorted,
                                                      const float* __restrict__ alphaPtr,
                                                      int* __restrict__ perm,
                                                      float* __restrict__ scaleArr,
                                                      float* __restrict__ out_probs) {
    __shared__ unsigned char cons[8192];
    __shared__ int wsum[16];
    __shared__ int woff[16];
    const int t = threadIdx.x, b = blockIdx.x;
    const int lane = t & 63, wv = t >> 6;
    const size_t base = (size_t)b * T_;
    const float alphaV = *alphaPtr;

    #pragma unroll
    for (int j = 0; j < 8; ++j) cons[(t << 3) + j] = 0;
    __syncthreads();

    for (int e = 0; e < E_; ++e) {
        const u64* sk = sorted + (((size_t)(b << 2) + e) << 13);
        u64 k[8]; int idx[8]; int f[8];
        int s = 0;
        #pragma unroll
        for (int j = 0; j < 8; ++j) {
            k[j] = sk[(t << 3) + j];
            idx[j] = 8191 - (int)(k[j] & 8191ull);
            f[j] = cons[idx[j]] ? 0 : 1;
            s += f[j];
        }
        int inc = s;
        #pragma unroll
        for (int o = 1; o < 64; o <<= 1) {
            int v = __shfl_up(inc, o, 64);
            if (lane >= o) inc += v;
        }
        if (lane == 63) wsum[wv] = inc;
        __syncthreads();
        if (t == 0) {
            int acc = 0;
            for (int w = 0; w < 16; ++w) { int v = wsum[w]; woff[w] = acc; acc += v; }
        }
        __syncthreads();
        int off = woff[wv] + (inc - s);   // thread-exclusive prefix
        #pragma unroll
        for (int j = 0; j < 8; ++j) {
            if (f[j] && off < 2048) {
                int rank = off;
                unsigned vb = (unsigned)(k[j] >> 13) - 1u;
                float v; __builtin_memcpy(&v, &vb, 4);
                int rpos = (e << 14) + (b << 11) + rank;
                perm[rpos] = idx[j];
                scaleArr[rpos] = alphaV * v + 1.0f;
                size_t g = ((size_t)b << 13) + (e << 11) + rank;
                float4 pr = *(const float4*)(rp + ((base + idx[j]) << 2));
                *(float4*)(out_probs + (g << 2)) = pr;
                cons[idx[j]] = 1;
            }
            off += f[j];
        }
        __syncthreads();
    }
}

// ---------------------------------------------------------------------------
// gather + LayerNorm. One wave per slot r'. Writes xn (bf16, [65536][512])
// and prefills out[g] = xi.
// ---------------------------------------------------------------------------
__global__ __launch_bounds__(256) void gather_ln(const float* __restrict__ x,
                                                 const int* __restrict__ perm,
                                                 const float* __restrict__ ln_w,
                                                 const float* __restrict__ ln_b,
                                                 short* __restrict__ xn,
                                                 float* __restrict__ out_outs) {
    const int wv = threadIdx.x >> 6, lane = threadIdx.x & 63;
    const int rp_ = (blockIdx.x << 2) + wv;
    const int e = rp_ >> 14, rem = rp_ & 16383, b = rem >> 11, rank = rem & 2047;
    const int idx = perm[rp_];
    const float* xr = x + (((size_t)b << 13) + idx) * D_;
    const int d0 = lane << 3;
    float4 v0 = *(const float4*)(xr + d0);
    float4 v1 = *(const float4*)(xr + d0 + 4);

    float s = v0.x + v0.y + v0.z + v0.w + v1.x + v1.y + v1.z + v1.w;
    #pragma unroll
    for (int o = 32; o > 0; o >>= 1) s += __shfl_xor(s, o, 64);
    float mu = s * (1.0f / 512.0f);

    float a0 = v0.x - mu, a1 = v0.y - mu, a2 = v0.z - mu, a3 = v0.w - mu;
    float a4 = v1.x - mu, a5 = v1.y - mu, a6 = v1.z - mu, a7 = v1.w - mu;
    float q = a0*a0 + a1*a1 + a2*a2 + a3*a3 + a4*a4 + a5*a5 + a6*a6 + a7*a7;
    #pragma unroll
    for (int o = 32; o > 0; o >>= 1) q += __shfl_xor(q, o, 64);
    float rstd = rsqrtf(q * (1.0f / 512.0f) + 1e-5f);

    const size_t g = ((size_t)b << 13) + (e << 11) + rank;
    float* op = out_outs + g * D_ + d0;
    *(float4*)op       = v0;            // residual prefill
    *(float4*)(op + 4) = v1;

    float4 w0 = *(const float4*)(ln_w + d0);
    float4 w1 = *(const float4*)(ln_w + d0 + 4);
    float4 bb0 = *(const float4*)(ln_b + d0);
    float4 bb1 = *(const float4*)(ln_b + d0 + 4);
    bf16x8 hv;
    hv[0] = f2bf(a0 * rstd * w0.x + bb0.x);
    hv[1] = f2bf(a1 * rstd * w0.y + bb0.y);
    hv[2] = f2bf(a2 * rstd * w0.z + bb0.z);
    hv[3] = f2bf(a3 * rstd * w0.w + bb0.w);
    hv[4] = f2bf(a4 * rstd * w1.x + bb1.x);
    hv[5] = f2bf(a5 * rstd * w1.y + bb1.y);
    hv[6] = f2bf(a6 * rstd * w1.z + bb1.z);
    hv[7] = f2bf(a7 * rstd * w1.w + bb1.w);
    *(bf16x8*)(xn + (size_t)rp_ * D_ + d0) = hv;
}

// ---------------------------------------------------------------------------
// GEMM, C = A(MxK) * B(NxK)^T, K-contiguous bf16. global_load_lds staging,
// XOR-swizzled LDS (slot ^= row&7 per 8-row chunk; pre-swizzled global source
// + swizzled ds_read -- both sides, same involution).
// 128x128 tile, BK=64, 4 waves, 4x4 frags of mfma_f32_16x16x32_bf16.
// MODE 1: h_e = bf16(gelu(C + l1_b[col]))            (N=2048, K=512>>e)
// MODE 2: out += scale * (C + l2_b[col]), split-K    (N=512>>e, K=2048)
// Expert e = expertArg + blockIdx.z; per-expert A/H slice via hStride.
// ---------------------------------------------------------------------------
template <int MODE>
__global__ __launch_bounds__(256) void gemm_bt(const short* __restrict__ A,
                                               const short* __restrict__ B,
                                               int lda, int ldb,
                                               const float* __restrict__ bias,
                                               short* __restrict__ H,
                                               float* __restrict__ Out,
                                               const float* __restrict__ scaleArr,
                                               int expertArg, size_t hStride) {
    __shared__ short As[128 * 64];
    __shared__ short Bs[128 * 64];
    const int t = threadIdx.x;
    const int lane = t & 63, wave = t >> 6;
    const int e = expertArg + blockIdx.z;
    const int tile_m = blockIdx.y << 7;

    int tile_n, kStart, nsteps, Ncols, sp;
    bool useAtomic;
    const short* Abase;
    if (MODE == 1) {
        tile_n = blockIdx.x << 7;
        kStart = 0;
        nsteps = (512 >> e) >> 6;            // 8,4,2,1
        Ncols  = 2048;
        Abase  = A + (size_t)e * M_TOK * D_; // xn slice
        sp = 0; useAtomic = false;
    } else {
        Ncols = 512 >> e;
        int se = e < 2 ? e : 2;              // log2 splits: 0,1,2,2
        int splits = 1 << se;
        int sub = blockIdx.x;                // 0..3  (ntiles*splits == 4 always)
        int nt = sub >> se;
        sp = sub & (splits - 1);
        tile_n = nt << 7;
        int Kslice = 2048 >> se;
        kStart = sp * Kslice;
        nsteps = Kslice >> 6;
        Abase  = A + (size_t)e * hStride;    // h slice
        useAtomic = (splits > 1);
    }

    // staging addresses (pre-swizzled source column), hoisted out of k-loop
    const int srow = lane >> 3;                       // row in 8-row chunk
    const int scol = ((lane & 7) ^ srow) << 3;        // permuted 8-elem slot
    const short* aP[4];
    const short* bP[4];
    #pragma unroll
    for (int q = 0; q < 4; ++q) {
        int c = (wave << 2) + q;
        aP[q] = Abase + (size_t)(tile_m + (c << 3) + srow) * lda + kStart + scol;
        bP[q] = B     + (size_t)(tile_n + (c << 3) + srow) * ldb + kStart + scol;
    }

    const int wm = (wave >> 1) << 6, wn = (wave & 1) << 6;
    const int lrow = lane & 15, lt = lane >> 4;
    const int sx = lrow & 7;                          // read-side XOR

    f32x4 acc[4][4];
    #pragma unroll
    for (int i = 0; i < 4; ++i)
        #pragma unroll
        for (int j = 0; j < 4; ++j)
            acc[i][j] = (f32x4){0.f, 0.f, 0.f, 0.f};

    for (int ks = 0; ks < nsteps; ++ks) {
        #pragma unroll
        for (int q = 0; q < 4; ++q) {
            int c = (wave << 2) + q;
            __builtin_amdgcn_global_load_lds(
                (const __attribute__((address_space(1))) unsigned int*)aP[q],
                (__attribute__((address_space(3))) unsigned int*)(As + (c << 9)),
                16, 0, 0);
            __builtin_amdgcn_global_load_lds(
                (const __attribute__((address_space(1))) unsigned int*)bP[q],
                (__attribute__((address_space(3))) unsigned int*)(Bs + (c << 9)),
                16, 0, 0);
            aP[q] += 64; bP[q] += 64;
        }
        __syncthreads();
        bf16x8 af[4][2], bfr[4][2];
        #pragma unroll
        for (int f = 0; f < 4; ++f)
            #pragma unroll
            for (int kk = 0; kk < 2; ++kk) {
                int slot = (kk << 2) + lt;
                af[f][kk]  = *(const bf16x8*)(As + ((wm + (f << 4) + lrow) << 6) + ((slot ^ sx) << 3));
                bfr[f][kk] = *(const bf16x8*)(Bs + ((wn + (f << 4) + lrow) << 6) + ((slot ^ sx) << 3));
            }
        #pragma unroll
        for (int kk = 0; kk < 2; ++kk)
            #pragma unroll
            for (int fm = 0; fm < 4; ++fm)
                #pragma unroll
                for (int fn = 0; fn < 4; ++fn)
                    acc[fm][fn] = __builtin_amdgcn_mfma_f32_16x16x32_bf16(
                        af[fm][kk], bfr[fn][kk], acc[fm][fn], 0, 0, 0);
        __syncthreads();
    }

    #pragma unroll
    for (int fm = 0; fm < 4; ++fm) {
        #pragma unroll
        for (int fn = 0; fn < 4; ++fn) {
            #pragma unroll
            for (int j = 0; j < 4; ++j) {
                int row = tile_m + wm + (fm << 4) + (lt << 2) + j;  // token (expert-local)
                int col = tile_n + wn + (fn << 4) + (lane & 15);
                float v = acc[fm][fn][j];
                if (MODE == 1) {
                    v += bias[col];
                    // gelu(v) = v * p/(p+1), p = exp(2*0.79788456*(v+0.044715 v^3))
                    float u = 1.5957691216f * v * (1.0f + 0.044715f * v * v);
                    u = fminf(u, 60.0f);
                    float p = __expf(u);
                    float g = v * p * __builtin_amdgcn_rcpf(p + 1.0f);
                    (H + (size_t)e * hStride)[(size_t)row * (size_t)INNER_ + col] = f2bf(g);
                } else {
                    if (col < Ncols) {
                        int bb = row >> 11, rank = row & 2047;
                        float sc = scaleArr[(e << 14) + row];
                        float val = sc * v + (sp == 0 ? sc * bias[col] : 0.0f);
                        float* p = Out + (((size_t)bb << 13) + (e << 11) + rank) * D_ + col;
                        if (useAtomic) atomicAdd(p, val);
                        else           *p += val;
                    }
                }
            }
        }
    }
}

// ---------------------------------------------------------------------------
extern "C" void kernel_launch(void* const* d_in, const int* in_sizes, int n_in,
                              void* d_out, int out_size, void* d_ws, size_t ws_size,
                              hipStream_t stream) {
    const float* x           = (const float*)d_in[0];
    const float* router_prob = (const float*)d_in[1];
    const float* alpha       = (const float*)d_in[2];
    const float* ln_w        = (const float*)d_in[3];
    const float* ln_b        = (const float*)d_in[4];
    const float* l1_w        = (const float*)d_in[5];
    const float* l1_b        = (const float*)d_in[6];
    const float* l2_w        = (const float*)d_in[7];
    const float* l2_b        = (const float*)d_in[8];

    float* out       = (float*)d_out;
    float* out_probs = out + (size_t)B_ * T_ * D_;

    char* ws = (char*)d_ws;
    int*   perm  = (int*)(ws);                                    // 256 KB
    float* scale = (float*)(ws + (1u << 18));                     // 256 KB
    short* w1b   = (short*)(ws + (2u << 18));                     // 2 MB
    short* w2b   = (short*)(ws + (2u << 18) + (1u << 21));        // 2 MB
    short* xn    = (short*)(ws + (2u << 18) + (2u << 21));        // 64 MB
    const size_t hOff = (size_t)(2u << 18) + (2u << 21) + (1u << 26);
    short* h     = (short*)(ws + hOff);                           // 64 or 256 MB
    u64*   sorted = (u64*)h;   // alias: consumed before h is first written

    const size_t hPerExpert = (size_t)M_TOK * INNER_;             // elements
    const bool fused = ws_size >= hOff + 4 * hPerExpert * sizeof(short);
    const size_t hStride = fused ? hPerExpert : 0;

    convertw<<<1024, 256, 0, stream>>>(l1_w, l2_w, w1b, w2b);
    sort_kernel<<<32, 1024, 0, stream>>>(router_prob, sorted);
    select_kernel<<<8, 1024, 0, stream>>>(router_prob, sorted, alpha, perm, scale, out_probs);
    gather_ln<<<16384, 256, 0, stream>>>(x, perm, ln_w, ln_b, xn, out);

    if (fused) {
        gemm_bt<1><<<dim3(16, 128, 4), 256, 0, stream>>>(
            xn, w1b, D_, D_, l1_b, h, nullptr, nullptr, 0, hStride);
        gemm_bt<2><<<dim3(4, 128, 4), 256, 0, stream>>>(
            h, w2b, INNER_, INNER_, l2_b, nullptr, out, scale, 0, hStride);
    } else {
        for (int e = 0; e < E_; ++e) {
            gemm_bt<1><<<dim3(16, 128, 1), 256, 0, stream>>>(
                xn, w1b, D_, D_, l1_b, h, nullptr, nullptr, e, 0);
            gemm_bt<2><<<dim3(4, 128, 1), 256, 0, stream>>>(
                h, w2b, INNER_, INNER_, l2_b, nullptr, out, scale, e, 0);
        }
    }
}